// Round 14
// baseline (178.189 us; speedup 1.0000x reference)
//
#include <hip/hip_runtime.h>

// Problem constants
#define BB    16
#define CC    256               // channels == embed dim
#define HWD   1024              // 32*32
#define NN    16384             // BB*HWD rows
#define KK    8192              // codebook size
#define DD    256               // embed dim
#define ZQ_N  4194304           // BB*CC*HWD output elements

// Workspace layout (bytes) -- TOTAL 131,080 B (proven)
#define WS_ROWBEST 0            // u64 rowBest[NN]   131,072 B
#define WS_LOSS    131072       // double lossSum          8 B
#define WS_NEEDED  131080

// Scratch inside d_out (float-index units). out_size = 4,210,691 floats.
#define ZB_OFF      0           // ushort zb[NN*DD]     floats [0 .. 2,097,152)
#define EB_OFF      2097152     // ushort eb[KK*DD]     floats [.. 3,145,728)
#define Q_OFF       3145728     // uint2 queue[64][SEGCAP]  (1,046,528 u32)
#define SEGCNT_OFF  4192256     // u32 segCnt[64]
#define BC_OFF      4194304     // u32 bestC[NN]        floats [.. 4,210,688)
#define SEGCAP      8176u       // entries per 256-row segment (8B each); 64*8176*8 = Q bytes
#define LQCAP       3072        // per-block LDS candidate list (exact overflow fallback)

#define CMARGIN  4e-4f   // >= 2*eps_tot (bf16 dot ~1e-4 + numpy-vs-coarse ~6.5e-5 + e2-omit 4e-6)

typedef short short8 __attribute__((ext_vector_type(8)));
typedef float f32x4  __attribute__((ext_vector_type(4)));
typedef unsigned short u16;
typedef unsigned int   u32;

// ---- helpers ----
static __device__ __forceinline__ u32 cenc(float x) {   // sortable f32
    u32 u = __float_as_uint(x);
    return (u & 0x80000000u) ? ~u : (u | 0x80000000u);
}
static __device__ __forceinline__ float cdec(u32 k) {
    u32 u = (k & 0x80000000u) ? (k ^ 0x80000000u) : ~k;
    return __uint_as_float(u);
}
static __device__ __forceinline__ u16 f2bf(float f) {    // RNE f32->bf16
    u32 u = __float_as_uint(f);
    return (u16)((u + 0x7FFFu + ((u >> 16) & 1u)) >> 16);
}

// Fused prologue: blocks [0,1024) = cvt_z, [1024,3072) = cvt_e, [3072,3136) = init.
__global__ __launch_bounds__(256)
void k_prep(const float* __restrict__ z, const float* __restrict__ emb,
            u16* __restrict__ zb, u16* __restrict__ eb,
            unsigned long long* __restrict__ rowBest, double* __restrict__ lossSum,
            u32* __restrict__ bestC, u32* __restrict__ segCnt) {
    __shared__ float tile[64][65];
    const int bid = blockIdx.x;
    const int t = threadIdx.x;
    if (bid < 1024) {
        // ---- cvt_z: z [b][d][hw] f32 -> zb16T [b*1024+hw][d] bf16 ----
        const int b = bid >> 6, d0 = ((bid >> 4) & 3) * 64, h0 = (bid & 15) * 64;
        const float* zp = z + ((size_t)b * CC + d0) * HWD + h0;
#pragma unroll
        for (int i = 0; i < 4; ++i) {
            int fid = i * 256 + t;
            int dd = fid >> 4, hq = (fid & 15) * 4;
            float4 v = *(const float4*)(zp + (size_t)dd * HWD + hq);
            tile[dd][hq] = v.x; tile[dd][hq + 1] = v.y; tile[dd][hq + 2] = v.z; tile[dd][hq + 3] = v.w;
        }
        __syncthreads();
        u16* op = zb + ((size_t)b * HWD + h0) * DD + d0;
#pragma unroll
        for (int i = 0; i < 4; ++i) {
            int fid = i * 256 + t;
            int hh = fid >> 4, dq = (fid & 15) * 4;
            ushort4 o;
            o.x = f2bf(tile[dq + 0][hh]); o.y = f2bf(tile[dq + 1][hh]);
            o.z = f2bf(tile[dq + 2][hh]); o.w = f2bf(tile[dq + 3][hh]);
            *(ushort4*)(op + (size_t)hh * DD + dq) = o;
        }
    } else if (bid < 3072) {
        // ---- cvt_e: emb f32 -> bf16 stream ----
        int i = (bid - 1024) * 256 + t;
        float4 v = ((const float4*)emb)[i];
        ushort4 o;
        o.x = f2bf(v.x); o.y = f2bf(v.y); o.z = f2bf(v.z); o.w = f2bf(v.w);
        ((ushort4*)eb)[i] = o;
    } else {
        // ---- init ----
        int i = (bid - 3072) * 256 + t;
        if (i < NN) {
            rowBest[i] = (((unsigned long long)0xFF800000u) << 24) | 0xFFFFFFULL; // +inf key
            bestC[i]   = 0xFFFFFFFFu;   // decodes NaN; all bound math NaN-safe (fminf)
        }
        if (i < 64) segCnt[i] = 0u;
        if (i == 64) *lossSum = 0.0;
    }
}

#define VMW4()  asm volatile("s_waitcnt vmcnt(4)"  ::: "memory")
#define VMW0()  asm volatile("s_waitcnt vmcnt(0)"  ::: "memory")
#define SBAR()  do { __builtin_amdgcn_s_barrier(); asm volatile("" ::: "memory"); } while (0)

// bf16 MFMA coarse GEMM, 256x256 tile, 8 waves (4x2), each wave 64x128 out
// (acc 4x8 -- r13's proven per-wave shape).  2048 blocks: sequential blocks
// per CU 16 -> 8, prologue fills + epilogue flush instances halved, per-work
// barrier count halved.  Waves/CU unchanged (8; 1 block x 8 waves vs r13's
// 2 x 4).  Single-barrier depth-2 ring: stage = 4 gloads/wave -> vmcnt(4);
// 3 buffers x 32KB = 96KB.  XCD-local row swizzle (bx = xcd*8 + ...),
// fmx-gated scan, returning-atomicMin bound.  Epilogue scratch aliases buf2
// after the vmcnt(0) drain.
__global__ __launch_bounds__(512, 2)
void k_gemm(const u16* __restrict__ zb, const u16* __restrict__ eb,
            u32* __restrict__ bestC, u32* __restrict__ segCnt, uint2* __restrict__ queue) {
    // 3 buffers x (A 16KB + B 16KB) = 96KB
    __shared__ __align__(16) char smem[98304];
    __shared__ u32 lqn, qbase;

    // XCD-local rows: xcd owns row-tiles [8*xcd, 8*xcd+8) of 64; col-tiles
    // (256 wide, 32 of them) sweep sequentially.
    const int bid = blockIdx.x;                   // 0..2047
    const int xcd = bid & 7, idx = bid >> 3;      // idx 0..255
    const int bx = xcd * 8 + (idx & 7);           // row-tile 0..63, XCD-local
    const int by = idx >> 3;                      // col-tile 0..31
    const int row0 = bx * 256, col0 = by * 256;

    const int t = threadIdx.x;
    const int wid = t >> 6, l = t & 63;
    const int wy = wid >> 1, wx = wid & 1;    // wave grid 4x2: 64 rows x 128 cols each

    f32x4 acc[4][8];
#pragma unroll
    for (int mi = 0; mi < 4; ++mi)
#pragma unroll
        for (int ni = 0; ni < 8; ++ni) acc[mi][ni] = (f32x4){0.f, 0.f, 0.f, 0.f};

    const int rbase = wid * 32;                       // this wave's staging rows (8 waves x 32 = 256)
    // Stage: 64B rows; LDS[r][c] holds global chunk c ^ ((r>>1)&3).
    const int srow   = l >> 2;
    const int schunk = (l & 3) ^ ((l >> 3) & 3);      // lane-constant
    // Read: chunk g=(l>>4) of row base+(l&15) lives at ((l>>4)^((l>>1)&3))<<4
    const int rchunk = (((l >> 4) ^ ((l >> 1) & 3)) << 4);
    const int rrow   = l & 15;

    auto stage = [&](int buf, int kc) {               // 4 gloads per wave
        char* As = smem + buf * 32768;
        char* Bs = As + 16384;
#pragma unroll
        for (int j = 0; j < 2; ++j) {                 // A: 32 rows, 16/instr
            const int rl = rbase + j * 16 + srow;
            const u16* gA = zb + (size_t)(row0 + rl) * DD + kc + schunk * 8;
            __builtin_amdgcn_global_load_lds(
                (const __attribute__((address_space(1))) u32*)gA,
                (__attribute__((address_space(3))) u32*)(As + (rbase + j * 16) * 64), 16, 0, 0);
        }
#pragma unroll
        for (int j = 0; j < 2; ++j) {                 // B: 32 rows, 16/instr
            const int rl = rbase + j * 16 + srow;
            const u16* gB = eb + (size_t)(col0 + rl) * DD + kc + schunk * 8;
            __builtin_amdgcn_global_load_lds(
                (const __attribute__((address_space(1))) u32*)gB,
                (__attribute__((address_space(3))) u32*)(Bs + (rbase + j * 16) * 64), 16, 0, 0);
        }
    };

    auto compute = [&](int buf) {
        const char* As = smem + buf * 32768;
        const char* Bs = As + 16384;
        short8 a[4], b[8];
#pragma unroll
        for (int mi = 0; mi < 4; ++mi)
            a[mi] = *(const short8*)(As + (wy * 64 + mi * 16 + rrow) * 64 + rchunk);
#pragma unroll
        for (int ni = 0; ni < 8; ++ni)
            b[ni] = *(const short8*)(Bs + (wx * 128 + ni * 16 + rrow) * 64 + rchunk);
        __builtin_amdgcn_s_setprio(1);
#pragma unroll
        for (int mi = 0; mi < 4; ++mi)
#pragma unroll
            for (int ni = 0; ni < 8; ++ni)
                acc[mi][ni] = __builtin_amdgcn_mfma_f32_16x16x32_bf16(a[mi], b[ni], acc[mi][ni], 0, 0, 0);
        __builtin_amdgcn_s_setprio(0);
    };

    // prologue: 2 tiles in flight (8 loads/wave)
    stage(0, 0); stage(1, 32);
    // 8 phases, ONE barrier each, depth-2 counted vmcnt (never 0 until last)
    VMW4(); SBAR(); compute(0); stage(2, 64);
    VMW4(); SBAR(); compute(1); stage(0, 96);
    VMW4(); SBAR(); compute(2); stage(1, 128);
    VMW4(); SBAR(); compute(0); stage(2, 160);
    VMW4(); SBAR(); compute(1); stage(0, 192);
    VMW4(); SBAR(); compute(2); stage(1, 224);
    VMW4(); SBAR(); compute(0);
    VMW0(); SBAR(); compute(1);

    // ---- epilogue: scratch aliases buffer 2 (last written at phase 3, last
    // read at phase 5; the VMW0+barrier before phase 7 drained ALL loads;
    // phase-7 compute reads buffer 1 only -> disjoint) ----
    float* rm = (float*)(smem + 65536);         // [256][2] row-min, then fresh bound (2KB)
    u32* lqe  = (u32*)(smem + 65536 + 2048);    // candidate entries (12KB)
    u32* lqs  = lqe + LQCAP;                    // candidate scores  (12KB) ends @ 92160 < 98304

    // per-row coarse min (= -2 * max dot); keep pre-shuffle ni-max for gating
    float fmx[4][4];
#pragma unroll
    for (int mi = 0; mi < 4; ++mi)
#pragma unroll
        for (int r = 0; r < 4; ++r) {
            float v = fmaxf(fmaxf(acc[mi][0][r], acc[mi][1][r]), fmaxf(acc[mi][2][r], acc[mi][3][r]));
            v = fmaxf(v, fmaxf(fmaxf(acc[mi][4][r], acc[mi][5][r]), fmaxf(acc[mi][6][r], acc[mi][7][r])));
            fmx[mi][r] = v;                      // max over this lane's 8 ni
            v = fmaxf(v, __shfl_xor(v, 1));
            v = fmaxf(v, __shfl_xor(v, 2));
            v = fmaxf(v, __shfl_xor(v, 4));
            v = fmaxf(v, __shfl_xor(v, 8));
            if ((l & 15) == 0)
                rm[(wy * 64 + mi * 16 + ((l >> 4) << 2) + r) * 2 + wx] = -2.0f * v;
        }
    __syncthreads();

    // fresh per-row bound: ONE coalesced returning atomicMin per row per block
    // (bestC lines are XCD-local under the row swizzle -> short RTT)
    if (t < 256) {
        float mn = fminf(rm[t * 2], rm[t * 2 + 1]);
        u32 old = atomicMin(bestC + row0 + t, cenc(mn));
        rm[t * 2] = fminf(mn, cdec(old));   // NaN-safe: fminf(x, NaN) = x
    }
    if (t == 0) lqn = 0;
    __syncthreads();

    uint2* qseg = queue + (size_t)bx * SEGCAP;

    // candidates (+scores) -> LDS list; exact overflow -> direct global slot
#pragma unroll
    for (int mi = 0; mi < 4; ++mi)
#pragma unroll
        for (int r = 0; r < 4; ++r) {
            const int rl = wy * 64 + mi * 16 + ((l >> 4) << 2) + r;
            const float cut = rm[rl * 2] + CMARGIN;
            if (-2.0f * fmx[mi][r] > cut) continue;   // lossless gate: min_ni(s) > cut
            const int row = row0 + rl;
#pragma unroll
            for (int ni = 0; ni < 8; ++ni) {
                const float s = -2.0f * acc[mi][ni][r];
                if (s <= cut) {
                    const int col = col0 + wx * 128 + ni * 16 + (l & 15);
                    u32 li = atomicAdd(&lqn, 1u);
                    if (li < LQCAP) {
                        lqe[li] = ((u32)row << 13) | (u32)col;
                        lqs[li] = __float_as_uint(s);
                    } else {
                        u32 gi = atomicAdd(segCnt + bx, 1u);   // rare exact fallback
                        if (gi < SEGCAP)
                            qseg[gi] = make_uint2(((u32)row << 13) | (u32)col, __float_as_uint(s));
                    }
                }
            }
        }
    __syncthreads();
    if (t == 0) {
        u32 n = min(lqn, (u32)LQCAP);
        lqn = n;
        qbase = atomicAdd(segCnt + bx, n);  // single reservation (XCD-local line)
    }
    __syncthreads();
    for (u32 i2 = t; i2 < lqn; i2 += 512) {
        u32 gi = qbase + i2;
        if (gi < SEGCAP) qseg[gi] = make_uint2(lqe[i2], lqs[i2]);
    }
}

// Row-centric rescore: block = (segment, 64-row quarter) -- single pass.  The
// block stages its 64-row z window in LDS ONCE via coalesced 256B runs, then
// scans ALL the segment's entries, filtering by row-window + final bestC
// bound, and runs the bit-exact numpy replica reading z from LDS.
__global__ __launch_bounds__(512)
void k_rescore(const float* __restrict__ z, const float* __restrict__ emb,
               const uint2* __restrict__ queue, const u32* __restrict__ segCnt,
               const u32* __restrict__ bestC,
               unsigned long long* __restrict__ rowBest) {
    __shared__ float zl[256][65];              // [d][row-in-window], +1 pad
    const int bid = blockIdx.x;                // 0..255
    const int seg  = bid >> 2;                 // 0..63 (256-row segments)
    const int quar = bid & 3;                  // 64-row quarter
    const int b = seg >> 2;                    // batch (4 segments per b)
    const int hwstart = ((seg & 3) << 8) + quar * 64;
    const int rlo = seg * 256 + quar * 64;     // global row window [rlo, rlo+64)

    // stage the 64-row z window: 256 d x 64 hw, coalesced 256B runs
    const float* zsrc = z + (size_t)b * CC * HWD + hwstart;
    const int t = threadIdx.x;
#pragma unroll
    for (int i = 0; i < 32; ++i) {
        int idx = i * 512 + t;                 // 0..16383
        int d = idx >> 6, j = idx & 63;
        zl[d][j] = zsrc[(size_t)d * HWD + j];
    }
    __syncthreads();

    const u32 n = min(segCnt[seg], SEGCAP);
    const uint2* q = queue + (size_t)seg * SEGCAP;
    for (u32 i = t; i < n; i += 512) {
        const uint2 ent = q[i];
        const int row = (int)(ent.x >> 13);
        const u32 r = (u32)(row - rlo);
        if (r >= 64u) continue;                // other quarter's row
        const int col = (int)(ent.x & 8191u);
        const float s = __uint_as_float(ent.y);
        const float bound = cdec(bestC[row]);  // final global coarse min (finite)
        if (s > bound + CMARGIN) continue;

        // ---- bit-exact numpy fp32 replica (validated) -- z from LDS ----
        const float* er = emb + (size_t)col * DD;

        float A0 = 0.f, A1 = 0.f, A2 = 0.f, A3 = 0.f;
        float zh0 = 0.f, eh0 = 0.f, z2 = 0.f, e2 = 0.f;
#pragma unroll
        for (int h = 0; h < 2; ++h) {
            const int base = h * 128;
            float zv[8], ev[8], rz[8], re[8];
#pragma unroll
            for (int q2 = 0; q2 < 8; ++q2) { zv[q2] = zl[base + q2][r]; ev[q2] = er[base + q2]; }
#pragma unroll
            for (int q2 = 0; q2 < 8; ++q2) { rz[q2] = __fmul_rn(zv[q2], zv[q2]); re[q2] = __fmul_rn(ev[q2], ev[q2]); }
            A0 = __fadd_rn(A0, __fmul_rn(zv[0], ev[0])); A1 = __fadd_rn(A1, __fmul_rn(zv[1], ev[1]));
            A2 = __fadd_rn(A2, __fmul_rn(zv[2], ev[2])); A3 = __fadd_rn(A3, __fmul_rn(zv[3], ev[3]));
            A0 = __fadd_rn(A0, __fmul_rn(zv[4], ev[4])); A1 = __fadd_rn(A1, __fmul_rn(zv[5], ev[5]));
            A2 = __fadd_rn(A2, __fmul_rn(zv[6], ev[6])); A3 = __fadd_rn(A3, __fmul_rn(zv[7], ev[7]));
            for (int i2 = 8; i2 < 128; i2 += 8) {
#pragma unroll
                for (int q2 = 0; q2 < 8; ++q2) { zv[q2] = zl[base + i2 + q2][r]; ev[q2] = er[base + i2 + q2]; }
#pragma unroll
                for (int q2 = 0; q2 < 8; ++q2) {
                    rz[q2] = __fadd_rn(rz[q2], __fmul_rn(zv[q2], zv[q2]));
                    re[q2] = __fadd_rn(re[q2], __fmul_rn(ev[q2], ev[q2]));
                }
                A0 = __fadd_rn(A0, __fmul_rn(zv[0], ev[0])); A1 = __fadd_rn(A1, __fmul_rn(zv[1], ev[1]));
                A2 = __fadd_rn(A2, __fmul_rn(zv[2], ev[2])); A3 = __fadd_rn(A3, __fmul_rn(zv[3], ev[3]));
                A0 = __fadd_rn(A0, __fmul_rn(zv[4], ev[4])); A1 = __fadd_rn(A1, __fmul_rn(zv[5], ev[5]));
                A2 = __fadd_rn(A2, __fmul_rn(zv[6], ev[6])); A3 = __fadd_rn(A3, __fmul_rn(zv[7], ev[7]));
            }
            float cz = __fadd_rn(__fadd_rn(__fadd_rn(rz[0], rz[1]), __fadd_rn(rz[2], rz[3])),
                                 __fadd_rn(__fadd_rn(rz[4], rz[5]), __fadd_rn(rz[6], rz[7])));
            float ce = __fadd_rn(__fadd_rn(__fadd_rn(re[0], re[1]), __fadd_rn(re[2], re[3])),
                                 __fadd_rn(__fadd_rn(re[4], re[5]), __fadd_rn(re[6], re[7])));
            if (h == 0) { zh0 = cz; eh0 = ce; }
            else        { z2 = __fadd_rn(zh0, cz); e2 = __fadd_rn(eh0, ce); }
        }
        const float dot = __fadd_rn(__fadd_rn(A0, A1), __fadd_rn(A2, A3));
        const float S   = __fadd_rn(z2, e2);
        const float d   = __fsub_rn(S, __fmul_rn(2.0f, dot));

        const u32 db = __float_as_uint(d);
        const u32 kd = (db & 0x80000000u) ? ~db : (db | 0x80000000u);
        const unsigned long long pk = (((unsigned long long)kd) << 24) | (unsigned long long)col;
        atomicMin(rowBest + row, pk);   // fp32-equal d -> smaller col = numpy first-index
    }
}

// Fused gather + ids, float2-widened (G13: 8B/lane).  Block = (128-hw tile,
// b, c-quarter); each lane handles 2 consecutive hw.  h2==0 blocks also emit
// the ids output from the already-loaded idr[].  Fused fp64 loss partial.
__global__ __launch_bounds__(256)
void k_gather(const float* __restrict__ z, const float* __restrict__ emb,
              const unsigned long long* __restrict__ rowBest,
              float* __restrict__ outZq, double* __restrict__ lossSum,
              float* __restrict__ outIds) {   // outIds = out + ZQ_N + 3
    __shared__ float lt[128][65];
    __shared__ u32 idr[128];
    __shared__ double red[4];
    const int t = threadIdx.x;
    const int hw0 = blockIdx.x * 128, b = blockIdx.y;
    const int h2 = blockIdx.z;                // channel quarter 0..3
    const int w = t >> 6, l = t & 63;

    if (t < 128) {
        u32 id = (u32)(rowBest[b * HWD + hw0 + t] & 0xFFFFFFULL) & (KK - 1);
        idr[t] = id;
        if (h2 == 0) outIds[b * HWD + hw0 + t] = (float)id;   // ids output
    }
    __syncthreads();

    // stage the 128 needed emb quarter-rows: lt[r][0..63]
    const int rr = t >> 6, cc = t & 63;       // 4 rows staged per sweep
    for (int s = 0; s < 32; ++s) {
        const int r = s * 4 + rr;
        lt[r][cc] = emb[(size_t)idr[r] * DD + h2 * 64 + cc];
    }
    __syncthreads();

    double lsum = 0.0;
#pragma unroll
    for (int i = 0; i < 16; ++i) {
        const int cl = i * 4 + w;
        const int c  = h2 * 64 + cl;
        const size_t f = ((size_t)(b * CC + c)) * HWD + hw0 + 2 * l;
        const float2 zv = *(const float2*)(z + f);
        float2 zq;
        zq.x = lt[2 * l][cl];
        zq.y = lt[2 * l + 1][cl];
        *(float2*)(outZq + f) = zq;
        const double d0 = (double)zq.x - (double)zv.x;
        const double d1 = (double)zq.y - (double)zv.y;
        lsum += d0 * d0 + d1 * d1;
    }
#pragma unroll
    for (int o = 32; o; o >>= 1) lsum += __shfl_down(lsum, o);
    if (l == 0) red[w] = lsum;
    __syncthreads();
    if (t == 0) atomicAdd(lossSum, red[0] + red[1] + red[2] + red[3]);
}

__global__ void k_loss(const double* __restrict__ lossSum, float* __restrict__ outLoss) {
    double m = *lossSum / (double)ZQ_N;
    outLoss[0] = (float)(1.25 * m);   // loss = commitment + codebook
    outLoss[1] = (float)(0.25 * m);   // commitment (cost 0.25)
    outLoss[2] = (float)m;            // codebook
}

extern "C" void kernel_launch(void* const* d_in, const int* in_sizes, int n_in,
                              void* d_out, int out_size, void* d_ws, size_t ws_size,
                              hipStream_t stream) {
    const float* z   = (const float*)d_in[0];
    const float* emb = (const float*)d_in[1];
    float* out = (float*)d_out;
    char* ws = (char*)d_ws;

    if (ws_size < (size_t)WS_NEEDED) return;

    unsigned long long* rowBest = (unsigned long long*)(ws + WS_ROWBEST);
    double*             lossSum = (double*)(ws + WS_LOSS);
    u16*   zb     = (u16*)(out + ZB_OFF);
    u16*   eb     = (u16*)(out + EB_OFF);
    uint2* queue  = (uint2*)(out + Q_OFF);
    u32*   segCnt = (u32*)(out + SEGCNT_OFF);
    u32*   bestC  = (u32*)(out + BC_OFF);

    hipLaunchKernelGGL(k_prep,    dim3(3136),        dim3(256), 0, stream,
                       z, emb, zb, eb, rowBest, lossSum, bestC, segCnt);
    hipLaunchKernelGGL(k_gemm,    dim3(2048),        dim3(512), 0, stream, zb, eb, bestC, segCnt, queue);
    hipLaunchKernelGGL(k_rescore, dim3(256),         dim3(512), 0, stream, z, emb, queue, segCnt, bestC, rowBest);
    hipLaunchKernelGGL(k_gather,  dim3(8, 16, 4),    dim3(256), 0, stream,
                       z, emb, rowBest, out, lossSum, out + ZQ_N + 3);
    hipLaunchKernelGGL(k_loss,    dim3(1),           dim3(1),   0, stream, lossSum, out + ZQ_N);
}

// Round 15
// 167.840 us; speedup vs baseline: 1.0617x; 1.0617x over previous
//
#include <hip/hip_runtime.h>

// Problem constants
#define BB    16
#define CC    256               // channels == embed dim
#define HWD   1024              // 32*32
#define NN    16384             // BB*HWD rows
#define KK    8192              // codebook size
#define DD    256               // embed dim
#define ZQ_N  4194304           // BB*CC*HWD output elements

// Workspace layout (bytes) -- TOTAL 131,080 B (proven)
#define WS_ROWBEST 0            // u64 rowBest[NN]   131,072 B
#define WS_LOSS    131072       // double lossSum          8 B
#define WS_NEEDED  131080

// Scratch inside d_out (float-index units). out_size = 4,210,691 floats.
#define ZB_OFF      0           // ushort zb[NN*DD]     floats [0 .. 2,097,152)
#define EB_OFF      2097152     // ushort eb[KK*DD]     floats [.. 3,145,728)
#define Q_OFF       3145728     // uint2 queue[128][SEGCAP]  (1,046,528 u32)
#define SEGCNT_OFF  4192256     // u32 segCnt[128]
#define BC_OFF      4194304     // u32 bestC[NN]        floats [.. 4,210,688)
#define SEGCAP      4088u       // entries per 128-row segment (8B each)
#define LQCAP       1536        // per-half LDS candidate list (exact overflow fallback)

#define CMARGIN  4e-4f   // >= 2*eps_tot (bf16 dot ~1e-4 + numpy-vs-coarse ~6.5e-5 + e2-omit 4e-6)

typedef short short8 __attribute__((ext_vector_type(8)));
typedef float f32x4  __attribute__((ext_vector_type(4)));
typedef unsigned short u16;
typedef unsigned int   u32;

// ---- helpers ----
static __device__ __forceinline__ u32 cenc(float x) {   // sortable f32
    u32 u = __float_as_uint(x);
    return (u & 0x80000000u) ? ~u : (u | 0x80000000u);
}
static __device__ __forceinline__ float cdec(u32 k) {
    u32 u = (k & 0x80000000u) ? (k ^ 0x80000000u) : ~k;
    return __uint_as_float(u);
}
static __device__ __forceinline__ u16 f2bf(float f) {    // RNE f32->bf16
    u32 u = __float_as_uint(f);
    return (u16)((u + 0x7FFFu + ((u >> 16) & 1u)) >> 16);
}

// Fused prologue: blocks [0,1024) = cvt_z, [1024,3072) = cvt_e, [3072,3136) = init.
__global__ __launch_bounds__(256)
void k_prep(const float* __restrict__ z, const float* __restrict__ emb,
            u16* __restrict__ zb, u16* __restrict__ eb,
            unsigned long long* __restrict__ rowBest, double* __restrict__ lossSum,
            u32* __restrict__ bestC, u32* __restrict__ segCnt) {
    __shared__ float tile[64][65];
    const int bid = blockIdx.x;
    const int t = threadIdx.x;
    if (bid < 1024) {
        // ---- cvt_z: z [b][d][hw] f32 -> zb16T [b*1024+hw][d] bf16 ----
        const int b = bid >> 6, d0 = ((bid >> 4) & 3) * 64, h0 = (bid & 15) * 64;
        const float* zp = z + ((size_t)b * CC + d0) * HWD + h0;
#pragma unroll
        for (int i = 0; i < 4; ++i) {
            int fid = i * 256 + t;
            int dd = fid >> 4, hq = (fid & 15) * 4;
            float4 v = *(const float4*)(zp + (size_t)dd * HWD + hq);
            tile[dd][hq] = v.x; tile[dd][hq + 1] = v.y; tile[dd][hq + 2] = v.z; tile[dd][hq + 3] = v.w;
        }
        __syncthreads();
        u16* op = zb + ((size_t)b * HWD + h0) * DD + d0;
#pragma unroll
        for (int i = 0; i < 4; ++i) {
            int fid = i * 256 + t;
            int hh = fid >> 4, dq = (fid & 15) * 4;
            ushort4 o;
            o.x = f2bf(tile[dq + 0][hh]); o.y = f2bf(tile[dq + 1][hh]);
            o.z = f2bf(tile[dq + 2][hh]); o.w = f2bf(tile[dq + 3][hh]);
            *(ushort4*)(op + (size_t)hh * DD + dq) = o;
        }
    } else if (bid < 3072) {
        // ---- cvt_e: emb f32 -> bf16 stream ----
        int i = (bid - 1024) * 256 + t;
        float4 v = ((const float4*)emb)[i];
        ushort4 o;
        o.x = f2bf(v.x); o.y = f2bf(v.y); o.z = f2bf(v.z); o.w = f2bf(v.w);
        ((ushort4*)eb)[i] = o;
    } else {
        // ---- init ----
        int i = (bid - 3072) * 256 + t;
        if (i < NN) {
            rowBest[i] = (((unsigned long long)0xFF800000u) << 24) | 0xFFFFFFULL; // +inf key
            bestC[i]   = 0xFFFFFFFFu;   // decodes NaN; all bound math NaN-safe (fminf)
        }
        if (i < 128) segCnt[i] = 0u;
        if (i == 128) *lossSum = 0.0;
    }
}

#define VMW4()  asm volatile("s_waitcnt vmcnt(4)"  ::: "memory")
#define VMW0()  asm volatile("s_waitcnt vmcnt(0)"  ::: "memory")
#define SBAR()  do { __builtin_amdgcn_s_barrier(); asm volatile("" ::: "memory"); } while (0)

// bf16 MFMA coarse GEMM, 256x256 tile, 8 waves (4x2), each wave 64x128 out
// (r14's K-loop, 134us -- kept verbatim).  r15 change: the epilogue keeps TWO
// per-half LDS candidate lists (rows [0,128) = waves wy<2, rows [128,256) =
// wy>=2; half is wave-uniform) and flushes each with its own single
// reservation into its own 128-row segment (2bx, 2bx+1).  This restores the
// proven 128x4088 queue granularity so k_rescore's scan work is halved back
// to the r13 level (the 64x8176 layout doubled it -- the r14 regression).
__global__ __launch_bounds__(512, 2)
void k_gemm(const u16* __restrict__ zb, const u16* __restrict__ eb,
            u32* __restrict__ bestC, u32* __restrict__ segCnt, uint2* __restrict__ queue) {
    // 3 buffers x (A 16KB + B 16KB) = 96KB
    __shared__ __align__(16) char smem[98304];
    __shared__ u32 lqn0, lqn1, qb0, qb1;

    // XCD-local rows: xcd owns row-tiles [8*xcd, 8*xcd+8) of 64; col-tiles
    // (256 wide, 32 of them) sweep sequentially.
    const int bid = blockIdx.x;                   // 0..2047
    const int xcd = bid & 7, idx = bid >> 3;      // idx 0..255
    const int bx = xcd * 8 + (idx & 7);           // row-tile 0..63, XCD-local
    const int by = idx >> 3;                      // col-tile 0..31
    const int row0 = bx * 256, col0 = by * 256;

    const int t = threadIdx.x;
    const int wid = t >> 6, l = t & 63;
    const int wy = wid >> 1, wx = wid & 1;    // wave grid 4x2: 64 rows x 128 cols each

    f32x4 acc[4][8];
#pragma unroll
    for (int mi = 0; mi < 4; ++mi)
#pragma unroll
        for (int ni = 0; ni < 8; ++ni) acc[mi][ni] = (f32x4){0.f, 0.f, 0.f, 0.f};

    const int rbase = wid * 32;                       // this wave's staging rows (8 waves x 32 = 256)
    // Stage: 64B rows; LDS[r][c] holds global chunk c ^ ((r>>1)&3).
    const int srow   = l >> 2;
    const int schunk = (l & 3) ^ ((l >> 3) & 3);      // lane-constant
    // Read: chunk g=(l>>4) of row base+(l&15) lives at ((l>>4)^((l>>1)&3))<<4
    const int rchunk = (((l >> 4) ^ ((l >> 1) & 3)) << 4);
    const int rrow   = l & 15;

    auto stage = [&](int buf, int kc) {               // 4 gloads per wave
        char* As = smem + buf * 32768;
        char* Bs = As + 16384;
#pragma unroll
        for (int j = 0; j < 2; ++j) {                 // A: 32 rows, 16/instr
            const int rl = rbase + j * 16 + srow;
            const u16* gA = zb + (size_t)(row0 + rl) * DD + kc + schunk * 8;
            __builtin_amdgcn_global_load_lds(
                (const __attribute__((address_space(1))) u32*)gA,
                (__attribute__((address_space(3))) u32*)(As + (rbase + j * 16) * 64), 16, 0, 0);
        }
#pragma unroll
        for (int j = 0; j < 2; ++j) {                 // B: 32 rows, 16/instr
            const int rl = rbase + j * 16 + srow;
            const u16* gB = eb + (size_t)(col0 + rl) * DD + kc + schunk * 8;
            __builtin_amdgcn_global_load_lds(
                (const __attribute__((address_space(1))) u32*)gB,
                (__attribute__((address_space(3))) u32*)(Bs + (rbase + j * 16) * 64), 16, 0, 0);
        }
    };

    auto compute = [&](int buf) {
        const char* As = smem + buf * 32768;
        const char* Bs = As + 16384;
        short8 a[4], b[8];
#pragma unroll
        for (int mi = 0; mi < 4; ++mi)
            a[mi] = *(const short8*)(As + (wy * 64 + mi * 16 + rrow) * 64 + rchunk);
#pragma unroll
        for (int ni = 0; ni < 8; ++ni)
            b[ni] = *(const short8*)(Bs + (wx * 128 + ni * 16 + rrow) * 64 + rchunk);
        __builtin_amdgcn_s_setprio(1);
#pragma unroll
        for (int mi = 0; mi < 4; ++mi)
#pragma unroll
            for (int ni = 0; ni < 8; ++ni)
                acc[mi][ni] = __builtin_amdgcn_mfma_f32_16x16x32_bf16(a[mi], b[ni], acc[mi][ni], 0, 0, 0);
        __builtin_amdgcn_s_setprio(0);
    };

    // prologue: 2 tiles in flight (8 loads/wave)
    stage(0, 0); stage(1, 32);
    // 8 phases, ONE barrier each, depth-2 counted vmcnt (never 0 until last)
    VMW4(); SBAR(); compute(0); stage(2, 64);
    VMW4(); SBAR(); compute(1); stage(0, 96);
    VMW4(); SBAR(); compute(2); stage(1, 128);
    VMW4(); SBAR(); compute(0); stage(2, 160);
    VMW4(); SBAR(); compute(1); stage(0, 192);
    VMW4(); SBAR(); compute(2); stage(1, 224);
    VMW4(); SBAR(); compute(0);
    VMW0(); SBAR(); compute(1);

    // ---- epilogue: scratch aliases buffer 2 (the VMW0+barrier before phase 7
    // drained ALL loads; phase-7 compute reads buffer 1 only -> disjoint) ----
    float* rm = (float*)(smem + 65536);         // [256][2] row-min, then fresh bound (2KB)
    u32* lqe0 = (u32*)(smem + 65536 + 2048);    // half-0 entries (6KB)
    u32* lqs0 = lqe0 + LQCAP;                   // half-0 scores  (6KB)
    u32* lqe1 = lqs0 + LQCAP;                   // half-1 entries (6KB)
    u32* lqs1 = lqe1 + LQCAP;                   // half-1 scores  (6KB) ends @92160 < 98304

    // per-row coarse min (= -2 * max dot); keep pre-shuffle ni-max for gating
    float fmx[4][4];
#pragma unroll
    for (int mi = 0; mi < 4; ++mi)
#pragma unroll
        for (int r = 0; r < 4; ++r) {
            float v = fmaxf(fmaxf(acc[mi][0][r], acc[mi][1][r]), fmaxf(acc[mi][2][r], acc[mi][3][r]));
            v = fmaxf(v, fmaxf(fmaxf(acc[mi][4][r], acc[mi][5][r]), fmaxf(acc[mi][6][r], acc[mi][7][r])));
            fmx[mi][r] = v;                      // max over this lane's 8 ni
            v = fmaxf(v, __shfl_xor(v, 1));
            v = fmaxf(v, __shfl_xor(v, 2));
            v = fmaxf(v, __shfl_xor(v, 4));
            v = fmaxf(v, __shfl_xor(v, 8));
            if ((l & 15) == 0)
                rm[(wy * 64 + mi * 16 + ((l >> 4) << 2) + r) * 2 + wx] = -2.0f * v;
        }
    __syncthreads();

    // fresh per-row bound: ONE coalesced returning atomicMin per row per block
    // (bestC lines are XCD-local under the row swizzle -> short RTT)
    if (t < 256) {
        float mn = fminf(rm[t * 2], rm[t * 2 + 1]);
        u32 old = atomicMin(bestC + row0 + t, cenc(mn));
        rm[t * 2] = fminf(mn, cdec(old));   // NaN-safe: fminf(x, NaN) = x
    }
    if (t == 0) { lqn0 = 0; lqn1 = 0; }
    __syncthreads();

    // candidates (+scores) -> per-half LDS list (half = wy>>1, wave-uniform);
    // exact overflow -> direct slot in that half's 128-row segment
    {
        const int half = wy >> 1;                      // rows [half*128, half*128+128)
        u32* lqe = half ? lqe1 : lqe0;
        u32* lqs = half ? lqs1 : lqs0;
        u32* lqnp = half ? &lqn1 : &lqn0;
        uint2* qseg = queue + (size_t)(bx * 2 + half) * SEGCAP;
        u32* scp = segCnt + bx * 2 + half;
#pragma unroll
        for (int mi = 0; mi < 4; ++mi)
#pragma unroll
            for (int r = 0; r < 4; ++r) {
                const int rl = wy * 64 + mi * 16 + ((l >> 4) << 2) + r;
                const float cut = rm[rl * 2] + CMARGIN;
                if (-2.0f * fmx[mi][r] > cut) continue;   // lossless gate: min_ni(s) > cut
                const int row = row0 + rl;
#pragma unroll
                for (int ni = 0; ni < 8; ++ni) {
                    const float s = -2.0f * acc[mi][ni][r];
                    if (s <= cut) {
                        const int col = col0 + wx * 128 + ni * 16 + (l & 15);
                        u32 li = atomicAdd(lqnp, 1u);
                        if (li < LQCAP) {
                            lqe[li] = ((u32)row << 13) | (u32)col;
                            lqs[li] = __float_as_uint(s);
                        } else {
                            u32 gi = atomicAdd(scp, 1u);   // rare exact fallback
                            if (gi < SEGCAP)
                                qseg[gi] = make_uint2(((u32)row << 13) | (u32)col, __float_as_uint(s));
                        }
                    }
                }
            }
    }
    __syncthreads();
    if (t == 0) {
        u32 n = min(lqn0, (u32)LQCAP);
        lqn0 = n;
        qb0 = atomicAdd(segCnt + bx * 2, n);       // single reservation, half 0
    }
    if (t == 1) {
        u32 n = min(lqn1, (u32)LQCAP);
        lqn1 = n;
        qb1 = atomicAdd(segCnt + bx * 2 + 1, n);   // single reservation, half 1
    }
    __syncthreads();
    {
        uint2* qs0 = queue + (size_t)(bx * 2) * SEGCAP;
        for (u32 i2 = t; i2 < lqn0; i2 += 512) {
            u32 gi = qb0 + i2;
            if (gi < SEGCAP) qs0[gi] = make_uint2(lqe0[i2], lqs0[i2]);
        }
        uint2* qs1 = queue + (size_t)(bx * 2 + 1) * SEGCAP;
        for (u32 i2 = t; i2 < lqn1; i2 += 512) {
            u32 gi = qb1 + i2;
            if (gi < SEGCAP) qs1[gi] = make_uint2(lqe1[i2], lqs1[i2]);
        }
    }
}

// Row-centric rescore (r13-proven): block = (128-row segment, 64-row half).
// The block stages its 64-row z window in LDS ONCE via coalesced 256B runs,
// then scans ALL the segment's entries, filtering by row-window + final bestC
// bound, and runs the bit-exact numpy replica reading z from LDS.
__global__ __launch_bounds__(512)
void k_rescore(const float* __restrict__ z, const float* __restrict__ emb,
               const uint2* __restrict__ queue, const u32* __restrict__ segCnt,
               const u32* __restrict__ bestC,
               unsigned long long* __restrict__ rowBest) {
    __shared__ float zl[256][65];              // [d][row-in-window], +1 pad
    const int bid = blockIdx.x;                // 0..255
    const int seg  = bid >> 1;                 // 0..127
    const int half = bid & 1;                  // 64-row half of the 128-row segment
    const int b = seg >> 3;                    // batch (8 segments per b)
    const int hwstart = ((seg & 7) << 7) + half * 64;
    const int rlo = seg * 128 + half * 64;     // global row window [rlo, rlo+64)

    // stage the 64-row z window: 256 d x 64 hw, coalesced 256B runs
    const float* zsrc = z + (size_t)b * CC * HWD + hwstart;
    const int t = threadIdx.x;
#pragma unroll
    for (int i = 0; i < 32; ++i) {
        int idx = i * 512 + t;                 // 0..16383
        int d = idx >> 6, j = idx & 63;
        zl[d][j] = zsrc[(size_t)d * HWD + j];
    }
    __syncthreads();

    const u32 n = min(segCnt[seg], SEGCAP);
    const uint2* q = queue + (size_t)seg * SEGCAP;
    for (u32 i = t; i < n; i += 512) {
        const uint2 ent = q[i];
        const int row = (int)(ent.x >> 13);
        const u32 r = (u32)(row - rlo);
        if (r >= 64u) continue;                // other half's row
        const int col = (int)(ent.x & 8191u);
        const float s = __uint_as_float(ent.y);
        const float bound = cdec(bestC[row]);  // final global coarse min (finite)
        if (s > bound + CMARGIN) continue;

        // ---- bit-exact numpy fp32 replica (validated) -- z from LDS ----
        const float* er = emb + (size_t)col * DD;

        float A0 = 0.f, A1 = 0.f, A2 = 0.f, A3 = 0.f;
        float zh0 = 0.f, eh0 = 0.f, z2 = 0.f, e2 = 0.f;
#pragma unroll
        for (int h = 0; h < 2; ++h) {
            const int base = h * 128;
            float zv[8], ev[8], rz[8], re[8];
#pragma unroll
            for (int q2 = 0; q2 < 8; ++q2) { zv[q2] = zl[base + q2][r]; ev[q2] = er[base + q2]; }
#pragma unroll
            for (int q2 = 0; q2 < 8; ++q2) { rz[q2] = __fmul_rn(zv[q2], zv[q2]); re[q2] = __fmul_rn(ev[q2], ev[q2]); }
            A0 = __fadd_rn(A0, __fmul_rn(zv[0], ev[0])); A1 = __fadd_rn(A1, __fmul_rn(zv[1], ev[1]));
            A2 = __fadd_rn(A2, __fmul_rn(zv[2], ev[2])); A3 = __fadd_rn(A3, __fmul_rn(zv[3], ev[3]));
            A0 = __fadd_rn(A0, __fmul_rn(zv[4], ev[4])); A1 = __fadd_rn(A1, __fmul_rn(zv[5], ev[5]));
            A2 = __fadd_rn(A2, __fmul_rn(zv[6], ev[6])); A3 = __fadd_rn(A3, __fmul_rn(zv[7], ev[7]));
            for (int i2 = 8; i2 < 128; i2 += 8) {
#pragma unroll
                for (int q2 = 0; q2 < 8; ++q2) { zv[q2] = zl[base + i2 + q2][r]; ev[q2] = er[base + i2 + q2]; }
#pragma unroll
                for (int q2 = 0; q2 < 8; ++q2) {
                    rz[q2] = __fadd_rn(rz[q2], __fmul_rn(zv[q2], zv[q2]));
                    re[q2] = __fadd_rn(re[q2], __fmul_rn(ev[q2], ev[q2]));
                }
                A0 = __fadd_rn(A0, __fmul_rn(zv[0], ev[0])); A1 = __fadd_rn(A1, __fmul_rn(zv[1], ev[1]));
                A2 = __fadd_rn(A2, __fmul_rn(zv[2], ev[2])); A3 = __fadd_rn(A3, __fmul_rn(zv[3], ev[3]));
                A0 = __fadd_rn(A0, __fmul_rn(zv[4], ev[4])); A1 = __fadd_rn(A1, __fmul_rn(zv[5], ev[5]));
                A2 = __fadd_rn(A2, __fmul_rn(zv[6], ev[6])); A3 = __fadd_rn(A3, __fmul_rn(zv[7], ev[7]));
            }
            float cz = __fadd_rn(__fadd_rn(__fadd_rn(rz[0], rz[1]), __fadd_rn(rz[2], rz[3])),
                                 __fadd_rn(__fadd_rn(rz[4], rz[5]), __fadd_rn(rz[6], rz[7])));
            float ce = __fadd_rn(__fadd_rn(__fadd_rn(re[0], re[1]), __fadd_rn(re[2], re[3])),
                                 __fadd_rn(__fadd_rn(re[4], re[5]), __fadd_rn(re[6], re[7])));
            if (h == 0) { zh0 = cz; eh0 = ce; }
            else        { z2 = __fadd_rn(zh0, cz); e2 = __fadd_rn(eh0, ce); }
        }
        const float dot = __fadd_rn(__fadd_rn(A0, A1), __fadd_rn(A2, A3));
        const float S   = __fadd_rn(z2, e2);
        const float d   = __fsub_rn(S, __fmul_rn(2.0f, dot));

        const u32 db = __float_as_uint(d);
        const u32 kd = (db & 0x80000000u) ? ~db : (db | 0x80000000u);
        const unsigned long long pk = (((unsigned long long)kd) << 24) | (unsigned long long)col;
        atomicMin(rowBest + row, pk);   // fp32-equal d -> smaller col = numpy first-index
    }
}

// Fused gather + ids, float2-widened (G13: 8B/lane).  Block = (128-hw tile,
// b, c-quarter); each lane handles 2 consecutive hw.  h2==0 blocks also emit
// the ids output from the already-loaded idr[].  Fused fp64 loss partial.
__global__ __launch_bounds__(256)
void k_gather(const float* __restrict__ z, const float* __restrict__ emb,
              const unsigned long long* __restrict__ rowBest,
              float* __restrict__ outZq, double* __restrict__ lossSum,
              float* __restrict__ outIds) {   // outIds = out + ZQ_N + 3
    __shared__ float lt[128][65];
    __shared__ u32 idr[128];
    __shared__ double red[4];
    const int t = threadIdx.x;
    const int hw0 = blockIdx.x * 128, b = blockIdx.y;
    const int h2 = blockIdx.z;                // channel quarter 0..3
    const int w = t >> 6, l = t & 63;

    if (t < 128) {
        u32 id = (u32)(rowBest[b * HWD + hw0 + t] & 0xFFFFFFULL) & (KK - 1);
        idr[t] = id;
        if (h2 == 0) outIds[b * HWD + hw0 + t] = (float)id;   // ids output
    }
    __syncthreads();

    // stage the 128 needed emb quarter-rows: lt[r][0..63]
    const int rr = t >> 6, cc = t & 63;       // 4 rows staged per sweep
    for (int s = 0; s < 32; ++s) {
        const int r = s * 4 + rr;
        lt[r][cc] = emb[(size_t)idr[r] * DD + h2 * 64 + cc];
    }
    __syncthreads();

    double lsum = 0.0;
#pragma unroll
    for (int i = 0; i < 16; ++i) {
        const int cl = i * 4 + w;
        const int c  = h2 * 64 + cl;
        const size_t f = ((size_t)(b * CC + c)) * HWD + hw0 + 2 * l;
        const float2 zv = *(const float2*)(z + f);
        float2 zq;
        zq.x = lt[2 * l][cl];
        zq.y = lt[2 * l + 1][cl];
        *(float2*)(outZq + f) = zq;
        const double d0 = (double)zq.x - (double)zv.x;
        const double d1 = (double)zq.y - (double)zv.y;
        lsum += d0 * d0 + d1 * d1;
    }
#pragma unroll
    for (int o = 32; o; o >>= 1) lsum += __shfl_down(lsum, o);
    if (l == 0) red[w] = lsum;
    __syncthreads();
    if (t == 0) atomicAdd(lossSum, red[0] + red[1] + red[2] + red[3]);
}

__global__ void k_loss(const double* __restrict__ lossSum, float* __restrict__ outLoss) {
    double m = *lossSum / (double)ZQ_N;
    outLoss[0] = (float)(1.25 * m);   // loss = commitment + codebook
    outLoss[1] = (float)(0.25 * m);   // commitment (cost 0.25)
    outLoss[2] = (float)m;            // codebook
}

extern "C" void kernel_launch(void* const* d_in, const int* in_sizes, int n_in,
                              void* d_out, int out_size, void* d_ws, size_t ws_size,
                              hipStream_t stream) {
    const float* z   = (const float*)d_in[0];
    const float* emb = (const float*)d_in[1];
    float* out = (float*)d_out;
    char* ws = (char*)d_ws;

    if (ws_size < (size_t)WS_NEEDED) return;

    unsigned long long* rowBest = (unsigned long long*)(ws + WS_ROWBEST);
    double*             lossSum = (double*)(ws + WS_LOSS);
    u16*   zb     = (u16*)(out + ZB_OFF);
    u16*   eb     = (u16*)(out + EB_OFF);
    uint2* queue  = (uint2*)(out + Q_OFF);
    u32*   segCnt = (u32*)(out + SEGCNT_OFF);
    u32*   bestC  = (u32*)(out + BC_OFF);

    hipLaunchKernelGGL(k_prep,    dim3(3136),        dim3(256), 0, stream,
                       z, emb, zb, eb, rowBest, lossSum, bestC, segCnt);
    hipLaunchKernelGGL(k_gemm,    dim3(2048),        dim3(512), 0, stream, zb, eb, bestC, segCnt, queue);
    hipLaunchKernelGGL(k_rescore, dim3(256),         dim3(512), 0, stream, z, emb, queue, segCnt, bestC, rowBest);
    hipLaunchKernelGGL(k_gather,  dim3(8, 16, 4),    dim3(256), 0, stream,
                       z, emb, rowBest, out, lossSum, out + ZQ_N + 3);
    hipLaunchKernelGGL(k_loss,    dim3(1),           dim3(1),   0, stream, lossSum, out + ZQ_N);
}

// Round 16
// 164.289 us; speedup vs baseline: 1.0846x; 1.0216x over previous
//
#include <hip/hip_runtime.h>

// Problem constants
#define BB    16
#define CC    256               // channels == embed dim
#define HWD   1024              // 32*32
#define NN    16384             // BB*HWD rows
#define KK    8192              // codebook size
#define DD    256               // embed dim
#define ZQ_N  4194304           // BB*CC*HWD output elements

// Workspace layout (bytes) -- TOTAL 131,080 B (proven)
#define WS_ROWBEST 0            // u64 rowBest[NN]   131,072 B
#define WS_LOSS    131072       // double lossSum          8 B
#define WS_NEEDED  131080

// Scratch inside d_out (float-index units). out_size = 4,210,691 floats.
#define ZB_OFF      0           // ushort zb[NN*DD]     floats [0 .. 2,097,152)
#define EB_OFF      2097152     // ushort eb[KK*DD]     floats [.. 3,145,728)
#define Q_OFF       3145728     // uint2 queue[128][SEGCAP]  (1,046,528 u32)
#define SEGCNT_OFF  4192256     // u32 segCnt[128]
#define BC_OFF      4194304     // u32 bestC[NN]        floats [.. 4,210,688)
#define SEGCAP      4088u       // entries per row-block segment (8B each)
#define LQCAP       1536        // per-block LDS candidate list (exact overflow fallback)

#define CMARGIN  4e-4f   // >= 2*eps_tot (bf16 dot ~1e-4 + numpy-vs-coarse ~6.5e-5 + e2-omit 4e-6)

typedef short short8 __attribute__((ext_vector_type(8)));
typedef float f32x4  __attribute__((ext_vector_type(4)));
typedef unsigned short u16;
typedef unsigned int   u32;

// ---- helpers ----
static __device__ __forceinline__ u32 cenc(float x) {   // sortable f32
    u32 u = __float_as_uint(x);
    return (u & 0x80000000u) ? ~u : (u | 0x80000000u);
}
static __device__ __forceinline__ float cdec(u32 k) {
    u32 u = (k & 0x80000000u) ? (k ^ 0x80000000u) : ~k;
    return __uint_as_float(u);
}
static __device__ __forceinline__ u16 f2bf(float f) {    // RNE f32->bf16
    u32 u = __float_as_uint(f);
    return (u16)((u + 0x7FFFu + ((u >> 16) & 1u)) >> 16);
}

// Fused prologue: blocks [0,1024) = cvt_z, [1024,3072) = cvt_e, [3072,3136) = init.
__global__ __launch_bounds__(256)
void k_prep(const float* __restrict__ z, const float* __restrict__ emb,
            u16* __restrict__ zb, u16* __restrict__ eb,
            unsigned long long* __restrict__ rowBest, double* __restrict__ lossSum,
            u32* __restrict__ bestC, u32* __restrict__ segCnt) {
    __shared__ float tile[64][65];
    const int bid = blockIdx.x;
    const int t = threadIdx.x;
    if (bid < 1024) {
        // ---- cvt_z: z [b][d][hw] f32 -> zb16T [b*1024+hw][d] bf16 ----
        const int b = bid >> 6, d0 = ((bid >> 4) & 3) * 64, h0 = (bid & 15) * 64;
        const float* zp = z + ((size_t)b * CC + d0) * HWD + h0;
#pragma unroll
        for (int i = 0; i < 4; ++i) {
            int fid = i * 256 + t;
            int dd = fid >> 4, hq = (fid & 15) * 4;
            float4 v = *(const float4*)(zp + (size_t)dd * HWD + hq);
            tile[dd][hq] = v.x; tile[dd][hq + 1] = v.y; tile[dd][hq + 2] = v.z; tile[dd][hq + 3] = v.w;
        }
        __syncthreads();
        u16* op = zb + ((size_t)b * HWD + h0) * DD + d0;
#pragma unroll
        for (int i = 0; i < 4; ++i) {
            int fid = i * 256 + t;
            int hh = fid >> 4, dq = (fid & 15) * 4;
            ushort4 o;
            o.x = f2bf(tile[dq + 0][hh]); o.y = f2bf(tile[dq + 1][hh]);
            o.z = f2bf(tile[dq + 2][hh]); o.w = f2bf(tile[dq + 3][hh]);
            *(ushort4*)(op + (size_t)hh * DD + dq) = o;
        }
    } else if (bid < 3072) {
        // ---- cvt_e: emb f32 -> bf16 stream ----
        int i = (bid - 1024) * 256 + t;
        float4 v = ((const float4*)emb)[i];
        ushort4 o;
        o.x = f2bf(v.x); o.y = f2bf(v.y); o.z = f2bf(v.z); o.w = f2bf(v.w);
        ((ushort4*)eb)[i] = o;
    } else {
        // ---- init ----
        int i = (bid - 3072) * 256 + t;
        if (i < NN) {
            rowBest[i] = (((unsigned long long)0xFF800000u) << 24) | 0xFFFFFFULL; // +inf key
            bestC[i]   = 0xFFFFFFFFu;   // decodes NaN; all bound math NaN-safe (fminf)
        }
        if (i < 128) segCnt[i] = 0u;
        if (i == 128) *lossSum = 0.0;
    }
}

#define VMW6()  asm volatile("s_waitcnt vmcnt(6)"  ::: "memory")
#define VMW0()  asm volatile("s_waitcnt vmcnt(0)"  ::: "memory")
#define SBAR()  do { __builtin_amdgcn_s_barrier(); asm volatile("" ::: "memory"); } while (0)

// bf16 MFMA coarse GEMM, 128x256 tile, 4 waves (2x2), each wave 64x128 out
// (acc 4x8): 12 ds_read_b128 feed 32 MFMA per phase.  4096 blocks.
// Single-barrier depth-2 ring (r11): phase p = vmcnt(6) -> s_barrier ->
// compute(buf p%3) -> stage(buf (p+2)%3).  XCD-local row swizzle (r10),
// fmx-gated scan (r8), returning-atomicMin bound (r0).  LDS 72KB -> 2
// blocks/CU.  r13-proven configuration (best total: 165.2us) -- FROZEN.
__global__ __launch_bounds__(256, 2)
void k_gemm(const u16* __restrict__ zb, const u16* __restrict__ eb,
            u32* __restrict__ bestC, u32* __restrict__ segCnt, uint2* __restrict__ queue) {
    // 3 buffers x (A 8KB + B 16KB) = 72KB
    __shared__ __align__(16) char smem[73728];
    __shared__ u32 lqn, qbase;

    // XCD-local rows: xcd owns row-tiles [16*xcd, 16*xcd+16); col-tiles (256
    // wide, 32 of them) sweep sequentially.
    const int bid = blockIdx.x;                   // 0..4095
    const int xcd = bid & 7, idx = bid >> 3;      // idx 0..511
    const int bx = xcd * 16 + (idx & 15);         // row-tile 0..127, XCD-local
    const int by = idx >> 4;                      // col-tile 0..31
    const int row0 = bx * 128, col0 = by * 256;

    const int t = threadIdx.x;
    const int wid = t >> 6, l = t & 63;
    const int wy = wid >> 1, wx = wid & 1;    // wave grid 2x2: 64 rows x 128 cols each

    f32x4 acc[4][8];
#pragma unroll
    for (int mi = 0; mi < 4; ++mi)
#pragma unroll
        for (int ni = 0; ni < 8; ++ni) acc[mi][ni] = (f32x4){0.f, 0.f, 0.f, 0.f};

    const int rbase = wid * 32;                       // this wave's A staging rows
    const int rbase2 = wid * 64;                      // this wave's B staging rows
    // Stage: 64B rows; LDS[r][c] holds global chunk c ^ ((r>>1)&3).
    const int srow   = l >> 2;
    const int schunk = (l & 3) ^ ((l >> 3) & 3);      // lane-constant
    // Read: chunk g=(l>>4) of row base+(l&15) lives at ((l>>4)^((l>>1)&3))<<4
    const int rchunk = (((l >> 4) ^ ((l >> 1) & 3)) << 4);
    const int rrow   = l & 15;

    auto stage = [&](int buf, int kc) {               // 6 gloads per wave
        char* As = smem + buf * 24576;
        char* Bs = As + 8192;
#pragma unroll
        for (int j = 0; j < 2; ++j) {                 // A: 32 rows, 16/instr
            const int rl = rbase + j * 16 + srow;
            const u16* gA = zb + (size_t)(row0 + rl) * DD + kc + schunk * 8;
            __builtin_amdgcn_global_load_lds(
                (const __attribute__((address_space(1))) u32*)gA,
                (__attribute__((address_space(3))) u32*)(As + (rbase + j * 16) * 64), 16, 0, 0);
        }
#pragma unroll
        for (int j = 0; j < 4; ++j) {                 // B: 64 rows, 16/instr
            const int rl = rbase2 + j * 16 + srow;
            const u16* gB = eb + (size_t)(col0 + rl) * DD + kc + schunk * 8;
            __builtin_amdgcn_global_load_lds(
                (const __attribute__((address_space(1))) u32*)gB,
                (__attribute__((address_space(3))) u32*)(Bs + (rbase2 + j * 16) * 64), 16, 0, 0);
        }
    };

    auto compute = [&](int buf) {
        const char* As = smem + buf * 24576;
        const char* Bs = As + 8192;
        short8 a[4], b[8];
#pragma unroll
        for (int mi = 0; mi < 4; ++mi)
            a[mi] = *(const short8*)(As + (wy * 64 + mi * 16 + rrow) * 64 + rchunk);
#pragma unroll
        for (int ni = 0; ni < 8; ++ni)
            b[ni] = *(const short8*)(Bs + (wx * 128 + ni * 16 + rrow) * 64 + rchunk);
        __builtin_amdgcn_s_setprio(1);
#pragma unroll
        for (int mi = 0; mi < 4; ++mi)
#pragma unroll
            for (int ni = 0; ni < 8; ++ni)
                acc[mi][ni] = __builtin_amdgcn_mfma_f32_16x16x32_bf16(a[mi], b[ni], acc[mi][ni], 0, 0, 0);
        __builtin_amdgcn_s_setprio(0);
    };

    // prologue: 2 tiles in flight (12 loads/wave)
    stage(0, 0); stage(1, 32);
    // 8 phases, ONE barrier each, depth-2 counted vmcnt (never 0 until last)
    VMW6(); SBAR(); compute(0); stage(2, 64);
    VMW6(); SBAR(); compute(1); stage(0, 96);
    VMW6(); SBAR(); compute(2); stage(1, 128);
    VMW6(); SBAR(); compute(0); stage(2, 160);
    VMW6(); SBAR(); compute(1); stage(0, 192);
    VMW6(); SBAR(); compute(2); stage(1, 224);
    VMW6(); SBAR(); compute(0);
    VMW0(); SBAR(); compute(1);

    // ---- epilogue: scratch aliases buffer 2 (last staged at phase 3, last
    // read at phase 5; the VMW0+barrier before phase 7 drained ALL loads;
    // phase-7 compute reads buffer 1 only -> disjoint) ----
    float* rm = (float*)(smem + 49152);         // [128][2] row-min, then fresh bound
    u32* lqe  = (u32*)(smem + 49152 + 1024);    // candidate entries (6KB)
    u32* lqs  = lqe + LQCAP;                    // candidate scores  (6KB)

    // per-row coarse min (= -2 * max dot); keep pre-shuffle ni-max for gating
    float fmx[4][4];
#pragma unroll
    for (int mi = 0; mi < 4; ++mi)
#pragma unroll
        for (int r = 0; r < 4; ++r) {
            float v = fmaxf(fmaxf(acc[mi][0][r], acc[mi][1][r]), fmaxf(acc[mi][2][r], acc[mi][3][r]));
            v = fmaxf(v, fmaxf(fmaxf(acc[mi][4][r], acc[mi][5][r]), fmaxf(acc[mi][6][r], acc[mi][7][r])));
            fmx[mi][r] = v;                      // max over this lane's 8 ni
            v = fmaxf(v, __shfl_xor(v, 1));
            v = fmaxf(v, __shfl_xor(v, 2));
            v = fmaxf(v, __shfl_xor(v, 4));
            v = fmaxf(v, __shfl_xor(v, 8));
            if ((l & 15) == 0)
                rm[(wy * 64 + mi * 16 + ((l >> 4) << 2) + r) * 2 + wx] = -2.0f * v;
        }
    __syncthreads();

    // fresh per-row bound: ONE coalesced returning atomicMin per row per block
    // (bestC lines are XCD-local under the row swizzle -> short RTT)
    if (t < 128) {
        float mn = fminf(rm[t * 2], rm[t * 2 + 1]);
        u32 old = atomicMin(bestC + row0 + t, cenc(mn));
        rm[t * 2] = fminf(mn, cdec(old));   // NaN-safe: fminf(x, NaN) = x
    }
    if (t == 0) lqn = 0;
    __syncthreads();

    uint2* qseg = queue + (size_t)bx * SEGCAP;

    // candidates (+scores) -> LDS list; exact overflow -> direct global slot
#pragma unroll
    for (int mi = 0; mi < 4; ++mi)
#pragma unroll
        for (int r = 0; r < 4; ++r) {
            const int rl = wy * 64 + mi * 16 + ((l >> 4) << 2) + r;
            const float cut = rm[rl * 2] + CMARGIN;
            if (-2.0f * fmx[mi][r] > cut) continue;   // lossless gate: min_ni(s) > cut
            const int row = row0 + rl;
#pragma unroll
            for (int ni = 0; ni < 8; ++ni) {
                const float s = -2.0f * acc[mi][ni][r];
                if (s <= cut) {
                    const int col = col0 + wx * 128 + ni * 16 + (l & 15);
                    u32 li = atomicAdd(&lqn, 1u);
                    if (li < LQCAP) {
                        lqe[li] = ((u32)row << 13) | (u32)col;
                        lqs[li] = __float_as_uint(s);
                    } else {
                        u32 gi = atomicAdd(segCnt + bx, 1u);   // rare exact fallback
                        if (gi < SEGCAP)
                            qseg[gi] = make_uint2(((u32)row << 13) | (u32)col, __float_as_uint(s));
                    }
                }
            }
        }
    __syncthreads();
    if (t == 0) {
        u32 n = min(lqn, (u32)LQCAP);
        lqn = n;
        qbase = atomicAdd(segCnt + bx, n);  // single reservation (XCD-local line)
    }
    __syncthreads();
    for (u32 i2 = t; i2 < lqn; i2 += 256) {
        u32 gi = qbase + i2;
        if (gi < SEGCAP) qseg[gi] = make_uint2(lqe[i2], lqs[i2]);
    }
}

// Row-centric rescore: block = (128-row segment, 64-row half) -- single pass.
// The block stages its 64-row z window in LDS ONCE via coalesced float4 runs
// (G13: 16B/lane; same bytes, same LDS bits as the scalar version), then
// scans ALL the segment's entries, filtering by row-window + final bestC
// bound, and runs the bit-exact numpy replica reading z from LDS.
__global__ __launch_bounds__(512)
void k_rescore(const float* __restrict__ z, const float* __restrict__ emb,
               const uint2* __restrict__ queue, const u32* __restrict__ segCnt,
               const u32* __restrict__ bestC,
               unsigned long long* __restrict__ rowBest) {
    __shared__ float zl[256][65];              // [d][row-in-window], +1 pad
    const int bid = blockIdx.x;                // 0..255
    const int seg  = bid >> 1;                 // 0..127
    const int half = bid & 1;                  // 64-row half of the 128-row segment
    const int b = seg >> 3;                    // batch (8 segments per b)
    const int hwstart = ((seg & 7) << 7) + half * 64;
    const int rlo = seg * 128 + half * 64;     // global row window [rlo, rlo+64)

    // stage the 64-row z window: 256 d x 64 hw, float4 per lane (16B, aligned:
    // hwstart is a multiple of 64)
    const float* zsrc = z + (size_t)b * CC * HWD + hwstart;
    const int t = threadIdx.x;
#pragma unroll
    for (int i = 0; i < 8; ++i) {
        int idx = i * 512 + t;                 // 0..4095 float4s
        int d = idx >> 4, j4 = (idx & 15) * 4;
        float4 v = *(const float4*)(zsrc + (size_t)d * HWD + j4);
        zl[d][j4] = v.x; zl[d][j4 + 1] = v.y; zl[d][j4 + 2] = v.z; zl[d][j4 + 3] = v.w;
    }
    __syncthreads();

    const u32 n = min(segCnt[seg], SEGCAP);
    const uint2* q = queue + (size_t)seg * SEGCAP;
    for (u32 i = t; i < n; i += 512) {
        const uint2 ent = q[i];
        const int row = (int)(ent.x >> 13);
        const u32 r = (u32)(row - rlo);
        if (r >= 64u) continue;                // other half's row
        const int col = (int)(ent.x & 8191u);
        const float s = __uint_as_float(ent.y);
        const float bound = cdec(bestC[row]);  // final global coarse min (finite)
        if (s > bound + CMARGIN) continue;

        // ---- bit-exact numpy fp32 replica (validated) -- z from LDS ----
        const float* er = emb + (size_t)col * DD;

        float A0 = 0.f, A1 = 0.f, A2 = 0.f, A3 = 0.f;
        float zh0 = 0.f, eh0 = 0.f, z2 = 0.f, e2 = 0.f;
#pragma unroll
        for (int h = 0; h < 2; ++h) {
            const int base = h * 128;
            float zv[8], ev[8], rz[8], re[8];
#pragma unroll
            for (int q2 = 0; q2 < 8; ++q2) { zv[q2] = zl[base + q2][r]; ev[q2] = er[base + q2]; }
#pragma unroll
            for (int q2 = 0; q2 < 8; ++q2) { rz[q2] = __fmul_rn(zv[q2], zv[q2]); re[q2] = __fmul_rn(ev[q2], ev[q2]); }
            A0 = __fadd_rn(A0, __fmul_rn(zv[0], ev[0])); A1 = __fadd_rn(A1, __fmul_rn(zv[1], ev[1]));
            A2 = __fadd_rn(A2, __fmul_rn(zv[2], ev[2])); A3 = __fadd_rn(A3, __fmul_rn(zv[3], ev[3]));
            A0 = __fadd_rn(A0, __fmul_rn(zv[4], ev[4])); A1 = __fadd_rn(A1, __fmul_rn(zv[5], ev[5]));
            A2 = __fadd_rn(A2, __fmul_rn(zv[6], ev[6])); A3 = __fadd_rn(A3, __fmul_rn(zv[7], ev[7]));
            for (int i2 = 8; i2 < 128; i2 += 8) {
#pragma unroll
                for (int q2 = 0; q2 < 8; ++q2) { zv[q2] = zl[base + i2 + q2][r]; ev[q2] = er[base + i2 + q2]; }
#pragma unroll
                for (int q2 = 0; q2 < 8; ++q2) {
                    rz[q2] = __fadd_rn(rz[q2], __fmul_rn(zv[q2], zv[q2]));
                    re[q2] = __fadd_rn(re[q2], __fmul_rn(ev[q2], ev[q2]));
                }
                A0 = __fadd_rn(A0, __fmul_rn(zv[0], ev[0])); A1 = __fadd_rn(A1, __fmul_rn(zv[1], ev[1]));
                A2 = __fadd_rn(A2, __fmul_rn(zv[2], ev[2])); A3 = __fadd_rn(A3, __fmul_rn(zv[3], ev[3]));
                A0 = __fadd_rn(A0, __fmul_rn(zv[4], ev[4])); A1 = __fadd_rn(A1, __fmul_rn(zv[5], ev[5]));
                A2 = __fadd_rn(A2, __fmul_rn(zv[6], ev[6])); A3 = __fadd_rn(A3, __fmul_rn(zv[7], ev[7]));
            }
            float cz = __fadd_rn(__fadd_rn(__fadd_rn(rz[0], rz[1]), __fadd_rn(rz[2], rz[3])),
                                 __fadd_rn(__fadd_rn(rz[4], rz[5]), __fadd_rn(rz[6], rz[7])));
            float ce = __fadd_rn(__fadd_rn(__fadd_rn(re[0], re[1]), __fadd_rn(re[2], re[3])),
                                 __fadd_rn(__fadd_rn(re[4], re[5]), __fadd_rn(re[6], re[7])));
            if (h == 0) { zh0 = cz; eh0 = ce; }
            else        { z2 = __fadd_rn(zh0, cz); e2 = __fadd_rn(eh0, ce); }
        }
        const float dot = __fadd_rn(__fadd_rn(A0, A1), __fadd_rn(A2, A3));
        const float S   = __fadd_rn(z2, e2);
        const float d   = __fsub_rn(S, __fmul_rn(2.0f, dot));

        const u32 db = __float_as_uint(d);
        const u32 kd = (db & 0x80000000u) ? ~db : (db | 0x80000000u);
        const unsigned long long pk = (((unsigned long long)kd) << 24) | (unsigned long long)col;
        atomicMin(rowBest + row, pk);   // fp32-equal d -> smaller col = numpy first-index
    }
}

// Fused gather + ids, float2-widened (G13: 8B/lane).  Block = (128-hw tile,
// b, c-quarter); each lane handles 2 consecutive hw.  h2==0 blocks also emit
// the ids output from the already-loaded idr[].  Fused fp64 loss partial.
__global__ __launch_bounds__(256)
void k_gather(const float* __restrict__ z, const float* __restrict__ emb,
              const unsigned long long* __restrict__ rowBest,
              float* __restrict__ outZq, double* __restrict__ lossSum,
              float* __restrict__ outIds) {   // outIds = out + ZQ_N + 3
    __shared__ float lt[128][65];
    __shared__ u32 idr[128];
    __shared__ double red[4];
    const int t = threadIdx.x;
    const int hw0 = blockIdx.x * 128, b = blockIdx.y;
    const int h2 = blockIdx.z;                // channel quarter 0..3
    const int w = t >> 6, l = t & 63;

    if (t < 128) {
        u32 id = (u32)(rowBest[b * HWD + hw0 + t] & 0xFFFFFFULL) & (KK - 1);
        idr[t] = id;
        if (h2 == 0) outIds[b * HWD + hw0 + t] = (float)id;   // ids output
    }
    __syncthreads();

    // stage the 128 needed emb quarter-rows: lt[r][0..63]
    const int rr = t >> 6, cc = t & 63;       // 4 rows staged per sweep
    for (int s = 0; s < 32; ++s) {
        const int r = s * 4 + rr;
        lt[r][cc] = emb[(size_t)idr[r] * DD + h2 * 64 + cc];
    }
    __syncthreads();

    double lsum = 0.0;
#pragma unroll
    for (int i = 0; i < 16; ++i) {
        const int cl = i * 4 + w;
        const int c  = h2 * 64 + cl;
        const size_t f = ((size_t)(b * CC + c)) * HWD + hw0 + 2 * l;
        const float2 zv = *(const float2*)(z + f);
        float2 zq;
        zq.x = lt[2 * l][cl];
        zq.y = lt[2 * l + 1][cl];
        *(float2*)(outZq + f) = zq;
        const double d0 = (double)zq.x - (double)zv.x;
        const double d1 = (double)zq.y - (double)zv.y;
        lsum += d0 * d0 + d1 * d1;
    }
#pragma unroll
    for (int o = 32; o; o >>= 1) lsum += __shfl_down(lsum, o);
    if (l == 0) red[w] = lsum;
    __syncthreads();
    if (t == 0) atomicAdd(lossSum, red[0] + red[1] + red[2] + red[3]);
}

__global__ void k_loss(const double* __restrict__ lossSum, float* __restrict__ outLoss) {
    double m = *lossSum / (double)ZQ_N;
    outLoss[0] = (float)(1.25 * m);   // loss = commitment + codebook
    outLoss[1] = (float)(0.25 * m);   // commitment (cost 0.25)
    outLoss[2] = (float)m;            // codebook
}

extern "C" void kernel_launch(void* const* d_in, const int* in_sizes, int n_in,
                              void* d_out, int out_size, void* d_ws, size_t ws_size,
                              hipStream_t stream) {
    const float* z   = (const float*)d_in[0];
    const float* emb = (const float*)d_in[1];
    float* out = (float*)d_out;
    char* ws = (char*)d_ws;

    if (ws_size < (size_t)WS_NEEDED) return;

    unsigned long long* rowBest = (unsigned long long*)(ws + WS_ROWBEST);
    double*             lossSum = (double*)(ws + WS_LOSS);
    u16*   zb     = (u16*)(out + ZB_OFF);
    u16*   eb     = (u16*)(out + EB_OFF);
    uint2* queue  = (uint2*)(out + Q_OFF);
    u32*   segCnt = (u32*)(out + SEGCNT_OFF);
    u32*   bestC  = (u32*)(out + BC_OFF);

    hipLaunchKernelGGL(k_prep,    dim3(3136),        dim3(256), 0, stream,
                       z, emb, zb, eb, rowBest, lossSum, bestC, segCnt);
    hipLaunchKernelGGL(k_gemm,    dim3(4096),        dim3(256), 0, stream, zb, eb, bestC, segCnt, queue);
    hipLaunchKernelGGL(k_rescore, dim3(256),         dim3(512), 0, stream, z, emb, queue, segCnt, bestC, rowBest);
    hipLaunchKernelGGL(k_gather,  dim3(8, 16, 4),    dim3(256), 0, stream,
                       z, emb, rowBest, out, lossSum, out + ZQ_N + 3);
    hipLaunchKernelGGL(k_loss,    dim3(1),           dim3(1),   0, stream, lossSum, out + ZQ_N);
}